// Round 2
// baseline (8339.958 us; speedup 1.0000x reference)
//
#include <hip/hip_runtime.h>
#include <hip/hip_bf16.h>
#include <math.h>

using bf16 = __hip_bfloat16;

__device__ __forceinline__ float b2f(bf16 v){ return __bfloat162float(v); }
__device__ __forceinline__ bf16 f2b(float v){ return __float2bfloat16(v); }

template<int A> __device__ __forceinline__ float act_fn(float v){
  if constexpr (A==1) return fmaxf(v, 0.f);                  // relu
  else if constexpr (A==2) return v > 0.f ? v : 0.2f*v;      // leaky 0.2
  else if constexpr (A==3) return 1.f/(1.f+expf(-v));        // sigmoid
  else if constexpr (A==4) return tanhf(v);                  // tanh
  else return v;
}

// Direct conv, NCHW, stride 1, pad K/2. Up to 4 concatenated sources.
// dt: 0 = f32, 1 = bf16, 2 = warp-virtual (bilinear sample of net(f32,16ch) by flows(bf16,8ch))
// Block: 256 thr = 16x16, each thread 2x2 px, 16 output channels per blockIdx.y chunk.
template<int K, int A>
__global__ __launch_bounds__(256) void conv_direct(
    const void* __restrict__ s0, int c0, int d0,
    const void* __restrict__ s1, int c1, int d1,
    const void* __restrict__ s2, int c2, int d2,
    const void* __restrict__ s3, int c3, int d3,
    const bf16* __restrict__ flows,
    const float* __restrict__ Wt, const float* __restrict__ bias,
    void* __restrict__ out, int outf32, int Cout, int Cstride,
    int H, int W)
{
  constexpr int TILE = 32, S = TILE + K - 1, PAD = K/2;
  __shared__ float tin[S*S];
  __shared__ __align__(16) float wl[K*K*16];
  const int tid = threadIdx.x;
  const int tX = tid & 15, tY = tid >> 4;
  const int tilesx = W / TILE;
  const int bx = blockIdx.x % tilesx, by = blockIdx.x / tilesx;
  const int ox0 = bx*TILE, oy0 = by*TILE;
  const int chunk = blockIdx.y, b = blockIdx.z;
  const int Cin = c0 + c1 + c2 + c3;
  const int HW = H*W;

  float acc[16][4];
  #pragma unroll
  for (int i = 0; i < 16; ++i)
    #pragma unroll
    for (int j = 0; j < 4; ++j) acc[i][j] = 0.f;

  for (int ci = 0; ci < Cin; ++ci) {
    // resolve concat source (uniform across block)
    const void* sp; int cl, dt, cN;
    if (ci < c0)                 { sp = s0; cl = ci;          dt = d0; cN = c0; }
    else if (ci < c0+c1)         { sp = s1; cl = ci-c0;       dt = d1; cN = c1; }
    else if (ci < c0+c1+c2)      { sp = s2; cl = ci-c0-c1;    dt = d2; cN = c2; }
    else                         { sp = s3; cl = ci-c0-c1-c2; dt = d3; cN = c3; }

    if (dt == 2) {
      // warp-virtual: wrapped channel cl = l*16+c -> bilinear sample of net ch c by flow l
      const int l = cl >> 4, c = cl & 15;
      const float* npl = (const float*)sp + ((size_t)b*16 + c)*(size_t)HW;
      const bf16* fxp = flows + ((size_t)b*8 + 2*l)*(size_t)HW;
      const bf16* fyp = fxp + HW;
      for (int i = tid; i < S*S; i += 256) {
        const int yy = i / S, xx = i - (i/S)*S;
        const int gy = oy0 + yy - PAD, gx = ox0 + xx - PAD;
        float v = 0.f;
        if (gy >= 0 && gy < H && gx >= 0 && gx < W) {
          const size_t p = (size_t)gy*W + gx;
          const float fx = b2f(fxp[p]), fy = b2f(fyp[p]);
          const float vgx = (float)gx - fx, vgy = (float)gy - fy;
          const float gxn = 2.f*vgx/(float)(W-1) - 1.f;
          const float gyn = 2.f*vgy/(float)(H-1) - 1.f;
          const float ix = ((gxn+1.f)*(float)W - 1.f)*0.5f;
          const float iy = ((gyn+1.f)*(float)H - 1.f)*0.5f;
          const float x0f = floorf(ix), y0f = floorf(iy);
          const float wx1 = ix - x0f, wy1 = iy - y0f;
          const float wx0 = 1.f - wx1, wy0 = 1.f - wy1;
          const int x0 = (int)x0f, y0 = (int)y0f, x1 = x0+1, y1 = y0+1;
          const bool vx0 = (x0 >= 0) & (x0 < W), vx1 = (x1 >= 0) & (x1 < W);
          const bool vy0 = (y0 >= 0) & (y0 < H), vy1 = (y1 >= 0) & (y1 < H);
          const int xc0 = min(max(x0,0),W-1), xc1 = min(max(x1,0),W-1);
          const int yc0 = min(max(y0,0),H-1), yc1 = min(max(y1,0),H-1);
          const float w00 = wx0*wy0*((vx0&&vy0)?1.f:0.f);
          const float w10 = wx1*wy0*((vx1&&vy0)?1.f:0.f);
          const float w01 = wx0*wy1*((vx0&&vy1)?1.f:0.f);
          const float w11 = wx1*wy1*((vx1&&vy1)?1.f:0.f);
          v = w00*npl[(size_t)yc0*W+xc0] + w10*npl[(size_t)yc0*W+xc1]
            + w01*npl[(size_t)yc1*W+xc0] + w11*npl[(size_t)yc1*W+xc1];
        }
        tin[i] = v;
      }
    } else {
      const size_t chb = ((size_t)b*cN + cl)*(size_t)HW;
      for (int i = tid; i < S*S; i += 256) {
        const int yy = i / S, xx = i - (i/S)*S;
        const int gy = oy0 + yy - PAD, gx = ox0 + xx - PAD;
        float v = 0.f;
        if (gy >= 0 && gy < H && gx >= 0 && gx < W) {
          const size_t idx = chb + (size_t)gy*W + gx;
          v = dt ? b2f(((const bf16*)sp)[idx]) : ((const float*)sp)[idx];
        }
        tin[i] = v;
      }
    }
    // stage weights as [k][co] so inner loop reads contiguous float4
    for (int i = tid; i < K*K*16; i += 256) {
      const int k = i >> 4, co = i & 15;
      const int cog = chunk*16 + co;
      wl[i] = (cog < Cout) ? Wt[((size_t)cog*Cin + ci)*(K*K) + k] : 0.f;
    }
    __syncthreads();

    float win[(K+1)*(K+1)];
    const int wy = tY*2, wx = tX*2;
    #pragma unroll
    for (int r = 0; r < K+1; ++r)
      #pragma unroll
      for (int c = 0; c < K+1; ++c)
        win[r*(K+1)+c] = tin[(wy+r)*S + wx + c];

    #pragma unroll
    for (int ky = 0; ky < K; ++ky) {
      #pragma unroll
      for (int kx = 0; kx < K; ++kx) {
        const float v0 = win[ky*(K+1)+kx];
        const float v1 = win[ky*(K+1)+kx+1];
        const float v2 = win[(ky+1)*(K+1)+kx];
        const float v3 = win[(ky+1)*(K+1)+kx+1];
        const int kk = (ky*K+kx)*16;
        #pragma unroll
        for (int g = 0; g < 4; ++g) {
          const float4 wv = *(const float4*)&wl[kk + g*4];
          acc[g*4+0][0] += v0*wv.x; acc[g*4+0][1] += v1*wv.x; acc[g*4+0][2] += v2*wv.x; acc[g*4+0][3] += v3*wv.x;
          acc[g*4+1][0] += v0*wv.y; acc[g*4+1][1] += v1*wv.y; acc[g*4+1][2] += v2*wv.y; acc[g*4+1][3] += v3*wv.y;
          acc[g*4+2][0] += v0*wv.z; acc[g*4+2][1] += v1*wv.z; acc[g*4+2][2] += v2*wv.z; acc[g*4+2][3] += v3*wv.z;
          acc[g*4+3][0] += v0*wv.w; acc[g*4+3][1] += v1*wv.w; acc[g*4+3][2] += v2*wv.w; acc[g*4+3][3] += v3*wv.w;
        }
      }
    }
    __syncthreads();
  }

  const int oy = oy0 + tY*2, ox = ox0 + tX*2;
  #pragma unroll
  for (int co = 0; co < 16; ++co) {
    const int cog = chunk*16 + co;
    if (cog < Cout) {
      const float bv = bias ? bias[cog] : 0.f;
      const size_t ob = ((size_t)b*Cstride + cog)*(size_t)HW;
      #pragma unroll
      for (int dy = 0; dy < 2; ++dy)
        #pragma unroll
        for (int dx = 0; dx < 2; ++dx) {
          const float v = act_fn<A>(acc[co][dy*2+dx] + bv);
          const size_t o = ob + (size_t)(oy+dy)*W + (ox+dx);
          if (outf32) ((float*)out)[o] = v; else ((bf16*)out)[o] = f2b(v);
        }
    }
  }
}

// concat [wz|wr] weights and [bz|br] bias
__global__ void concat_zr(const float* __restrict__ wz, const float* __restrict__ wr,
                          const float* __restrict__ bz, const float* __restrict__ br,
                          float* __restrict__ wzr, float* __restrict__ bzr){
  const int n = 16*144*9;
  const int i = blockIdx.x*256 + threadIdx.x;
  if (i < n) { wzr[i] = wz[i]; wzr[n+i] = wr[i]; }
  if (i < 16) { bzr[i] = bz[i]; bzr[16+i] = br[i]; }
}

// rh = rg * net   (rg = channels 16..31 of zgrg)
__global__ void rh_kernel(const bf16* __restrict__ zgrg, const float* __restrict__ net,
                          bf16* __restrict__ rh, int HW){
  const int i = blockIdx.x*256 + threadIdx.x;
  const int c = blockIdx.y, b = blockIdx.z;
  if (i >= HW) return;
  const float rg = b2f(zgrg[((size_t)b*32 + 16 + c)*(size_t)HW + i]);
  const size_t o = ((size_t)b*16 + c)*(size_t)HW + i;
  rh[o] = f2b(rg * net[o]);
}

// h1 = (1-zg)*net + zg*q   (zg = channels 0..15 of zgrg), written f32 to d_out
__global__ void h1_kernel(const bf16* __restrict__ zgrg, const bf16* __restrict__ q,
                          const float* __restrict__ net, float* __restrict__ h1, int HW){
  const int i = blockIdx.x*256 + threadIdx.x;
  const int c = blockIdx.y, b = blockIdx.z;
  if (i >= HW) return;
  const float z = b2f(zgrg[((size_t)b*32 + c)*(size_t)HW + i]);
  const size_t o = ((size_t)b*16 + c)*(size_t)HW + i;
  h1[o] = (1.f - z)*net[o] + z*b2f(q[o]);
}

// per-(b,c) mean & max over HW
__global__ __launch_bounds__(256) void castats_kernel(const float* __restrict__ h1,
                                                      float* __restrict__ stats, int HW){
  const int bc = blockIdx.x;
  const float* p = h1 + (size_t)bc*(size_t)HW;
  float s = 0.f, m = -3.4e38f;
  for (int i = threadIdx.x; i < HW; i += 256) { const float v = p[i]; s += v; m = fmaxf(m, v); }
  #pragma unroll
  for (int o = 32; o >= 1; o >>= 1) { s += __shfl_down(s, o); m = fmaxf(m, __shfl_down(m, o)); }
  __shared__ float ss[4], sm[4];
  const int wave = threadIdx.x >> 6;
  if ((threadIdx.x & 63) == 0) { ss[wave] = s; sm[wave] = m; }
  __syncthreads();
  if (threadIdx.x == 0) {
    const float S = ss[0]+ss[1]+ss[2]+ss[3];
    const float M = fmaxf(fmaxf(sm[0],sm[1]), fmaxf(sm[2],sm[3]));
    stats[bc*2] = S/(float)HW; stats[bc*2+1] = M;
  }
}

// channel-attention scale
__global__ void cascale_kernel(const float* __restrict__ stats, const float* __restrict__ w1,
                               const float* __restrict__ w2, float* __restrict__ scale){
  const int t = threadIdx.x;       // 64 = 4b x 16c
  const int c = t & 15;
  float pa = w1[c]*stats[t*2], pm = w1[c]*stats[t*2+1];
  #pragma unroll
  for (int o = 8; o >= 1; o >>= 1) { pa += __shfl_xor(pa, o, 16); pm += __shfl_xor(pm, o, 16); }
  const float y = w2[c]*fmaxf(pa, 0.f) + w2[c]*fmaxf(pm, 0.f);
  scale[t] = 1.f/(1.f+expf(-y));
}

// per-pixel mean/max over 16 channels of h1*scale
__global__ void sastats_kernel(const float* __restrict__ h1, const float* __restrict__ scale,
                               bf16* __restrict__ sa2, int HW){
  const int i = blockIdx.x*256 + threadIdx.x;
  const int b = blockIdx.y;
  if (i >= HW) return;
  float s = 0.f, m = -3.4e38f;
  #pragma unroll
  for (int c = 0; c < 16; ++c) {
    const float v = h1[((size_t)b*16 + c)*(size_t)HW + i]*scale[b*16+c];
    s += v; m = fmaxf(m, v);
  }
  sa2[((size_t)b*2 + 0)*(size_t)HW + i] = f2b(s*(1.f/16.f));
  sa2[((size_t)b*2 + 1)*(size_t)HW + i] = f2b(m);
}

// 7x7 conv 2ch->1, pad 3, no bias, fused sigmoid
__global__ __launch_bounds__(256) void saconv_kernel(const bf16* __restrict__ sa2,
    const float* __restrict__ w, bf16* __restrict__ samap, int H, int W){
  __shared__ float wl[98];
  if (threadIdx.x < 98) wl[threadIdx.x] = w[threadIdx.x];
  __syncthreads();
  const int i = blockIdx.x*256 + threadIdx.x;
  const int b = blockIdx.y;
  const int HW = H*W;
  if (i >= HW) return;
  const int y = i / W, x = i - (i / W)*W;
  float s = 0.f;
  #pragma unroll
  for (int ch = 0; ch < 2; ++ch) {
    const size_t base = ((size_t)b*2 + ch)*(size_t)HW;
    for (int ky = 0; ky < 7; ++ky) {
      const int yy = y + ky - 3;
      if (yy < 0 || yy >= H) continue;
      for (int kx = 0; kx < 7; ++kx) {
        const int xx = x + kx - 3;
        if (xx < 0 || xx >= W) continue;
        s += b2f(sa2[base + (size_t)yy*W + xx]) * wl[ch*49 + ky*7 + kx];
      }
    }
  }
  samap[(size_t)b*(size_t)HW + i] = f2b(1.f/(1.f+expf(-s)));
}

// out_h *= scale * samap  (in place on d_out)
__global__ void hfinal_kernel(float* __restrict__ outh, const float* __restrict__ scale,
                              const bf16* __restrict__ samap, int HW){
  const int i = blockIdx.x*256 + threadIdx.x;
  const int b = blockIdx.y;
  if (i >= HW) return;
  const float sa = b2f(samap[(size_t)b*(size_t)HW + i]);
  #pragma unroll
  for (int c = 0; c < 16; ++c) {
    const size_t o = ((size_t)b*16 + c)*(size_t)HW + i;
    outh[o] = outh[o]*scale[b*16+c]*sa;
  }
}

struct SrcDesc { const void* p; int c; int dt; };

static inline void conv_launch(hipStream_t st, int K, int A,
  SrcDesc a, SrcDesc b, SrcDesc c, SrcDesc d, const bf16* flows,
  const float* Wt, const float* bias, void* out, int outf32, int Cout, int Cstride,
  int H, int W)
{
  dim3 grid((W/32)*(H/32), (Cout+15)/16, 4);
  #define CASE(KK,AA) if (K==KK && A==AA) { conv_direct<KK,AA><<<grid,256,0,st>>>( \
    a.p,a.c,a.dt, b.p,b.c,b.dt, c.p,c.c,c.dt, d.p,d.c,d.dt, flows, \
    Wt,bias,out,outf32,Cout,Cstride,H,W); return; }
  CASE(3,0) CASE(3,1) CASE(3,3) CASE(3,4) CASE(5,0) CASE(5,2)
  #undef CASE
}

extern "C" void kernel_launch(void* const* d_in, const int* in_sizes, int n_in,
                              void* d_out, int out_size, void* d_ws, size_t ws_size,
                              hipStream_t stream)
{
  const float* net   = (const float*)d_in[0];
  const float* inp   = (const float*)d_in[1];
  const float* corr  = (const float*)d_in[2];
  const float* noise = (const float*)d_in[3];
  const float* wc1 = (const float*)d_in[4];  const float* bc1 = (const float*)d_in[5];
  const float* wc2 = (const float*)d_in[6];  const float* bc2 = (const float*)d_in[7];
  const float* wf1 = (const float*)d_in[8];  const float* bf1 = (const float*)d_in[9];
  const float* wf2 = (const float*)d_in[10]; const float* bf2 = (const float*)d_in[11];
  const float* we  = (const float*)d_in[12]; const float* be  = (const float*)d_in[13];
  const float* loc1_w = (const float*)d_in[14]; const float* loc1_b = (const float*)d_in[15];
  const float* loc2_w = (const float*)d_in[16]; const float* loc2_b = (const float*)d_in[17];
  const float* wz = (const float*)d_in[18]; const float* bz = (const float*)d_in[19];
  const float* wr = (const float*)d_in[20]; const float* br = (const float*)d_in[21];
  const float* wq = (const float*)d_in[22]; const float* bq = (const float*)d_in[23];
  const float* ca_w1 = (const float*)d_in[24]; const float* ca_w2 = (const float*)d_in[25];
  const float* sa_w  = (const float*)d_in[26];
  const float* fh1_w = (const float*)d_in[27]; const float* fh1_b = (const float*)d_in[28];
  const float* fh2_w = (const float*)d_in[29]; const float* fh2_b = (const float*)d_in[30];

  const int B = 4, H = 512, W = 512, HW = H*W;
  char* ws = (char*)d_ws;
  const size_t MB = 1ull << 20;
  // Workspace: exactly [0, 256MB).
  //   M [0,128):   flo1 (transient) -> mo (61ch bf16) -> CBAM small buffers
  //   A [128,192): cor1 -> flo2 -> t -> zgrg(32ch)
  //   C [192,256): cor2 -> flows -> rh | q
  //   fh1o = A+C (128MB) at the end.
  bf16* mo    = (bf16*)(ws);
  bf16* flo1  = (bf16*)(ws);
  bf16* cor1  = (bf16*)(ws + 128*MB);
  bf16* flo2  = (bf16*)(ws + 128*MB);
  bf16* t     = (bf16*)(ws + 128*MB);
  bf16* zgrg  = (bf16*)(ws + 128*MB);
  bf16* cor2  = (bf16*)(ws + 192*MB);
  bf16* flows = (bf16*)(ws + 192*MB);
  bf16* rh    = (bf16*)(ws + 192*MB);
  bf16* q     = (bf16*)(ws + 224*MB);
  bf16* fh1o  = (bf16*)(ws + 128*MB);
  float* stats= (float*)(ws);                 // M region, mo dead by then
  float* scale= (float*)(ws + 64*1024);
  bf16* sa2   = (bf16*)(ws + 1*MB);
  bf16* samap = (bf16*)(ws + 5*MB);

  float* out_h  = (float*)d_out;
  float* out_df = out_h + (size_t)B*16*HW;
  // park concatenated z/r weights in the (not yet written) delta_flow output region
  float* wzr = out_df;
  float* bzr = wzr + 2*16*144*9;

  SrcDesc NONE{nullptr,0,0};

  concat_zr<<<(16*144*9 + 255)/256, 256, 0, stream>>>(wz, wr, bz, br, wzr, bzr);

  // --- BasicMotionEncoder ---
  conv_launch(stream,3,1, {corr,3,0},  NONE,NONE,NONE, nullptr, wc1,bc1, cor1,0, 32,32,H,W);
  conv_launch(stream,3,1, {cor1,32,1}, NONE,NONE,NONE, nullptr, wc2,bc2, cor2,0, 32,32,H,W);
  conv_launch(stream,3,1, {noise,3,0}, NONE,NONE,NONE, nullptr, wf1,bf1, flo1,0, 32,32,H,W);
  conv_launch(stream,3,1, {flo1,32,1}, NONE,NONE,NONE, nullptr, wf2,bf2, flo2,0, 32,32,H,W);
  conv_launch(stream,3,1, {cor2,32,1}, {flo2,32,1}, NONE,NONE, nullptr, we,be, mo,0, 61,61,H,W);

  // --- local flows ---
  conv_launch(stream,5,2, {inp,16,0}, {mo,61,1}, {noise,3,0}, {net,16,0}, nullptr,
              loc1_w,loc1_b, t,0, 16,16,H,W);
  conv_launch(stream,5,0, {t,16,1}, NONE,NONE,NONE, nullptr, loc2_w,loc2_b, flows,0, 8,8,H,W);

  // --- GRU (warp fused into conv staging via dt=2 virtual source) ---
  conv_launch(stream,3,3, {net,64,2}, {inp,16,0}, {mo,61,1}, {noise,3,0}, flows,
              wzr,bzr, zgrg,0, 32,32,H,W);
  rh_kernel<<<dim3(HW/256,16,B),256,0,stream>>>(zgrg, net, rh, HW);
  conv_launch(stream,3,4, {rh,16,1}, {inp,16,0}, {mo,61,1}, {noise,3,0}, nullptr,
              wq,bq, q,0, 16,16,H,W);
  h1_kernel<<<dim3(HW/256,16,B),256,0,stream>>>(zgrg, q, net, out_h, HW);

  // --- CBAM ---
  castats_kernel<<<64,256,0,stream>>>(out_h, stats, HW);
  cascale_kernel<<<1,64,0,stream>>>(stats, ca_w1, ca_w2, scale);
  sastats_kernel<<<dim3(HW/256,B),256,0,stream>>>(out_h, scale, sa2, HW);
  saconv_kernel<<<dim3(HW/256,B),256,0,stream>>>(sa2, sa_w, samap, H, W);
  hfinal_kernel<<<dim3(HW/256,B),256,0,stream>>>(out_h, scale, samap, HW);

  // --- FlowHead ---
  conv_launch(stream,3,1, {out_h,16,0}, NONE,NONE,NONE, nullptr, fh1_w,fh1_b, fh1o,0, 64,64,H,W);
  conv_launch(stream,3,0, {fh1o,64,1}, NONE,NONE,NONE, nullptr, fh2_w,fh2_b, out_df,1, 3,3,H,W);
}

// Round 3
// 3376.938 us; speedup vs baseline: 2.4697x; 2.4697x over previous
//
#include <hip/hip_runtime.h>
#include <hip/hip_bf16.h>
#include <math.h>

using bf16 = __hip_bfloat16;
typedef __attribute__((ext_vector_type(8))) short short8;
typedef __attribute__((ext_vector_type(4))) float f32x4;

__device__ __forceinline__ float b2f(bf16 v){ return __bfloat162float(v); }
__device__ __forceinline__ bf16 f2b(float v){ return __float2bfloat16(v); }

template<int A> __device__ __forceinline__ float act_fn(float v){
  if constexpr (A==1) return fmaxf(v, 0.f);                  // relu
  else if constexpr (A==2) return v > 0.f ? v : 0.2f*v;      // leaky 0.2
  else if constexpr (A==3) return 1.f/(1.f+expf(-v));        // sigmoid
  else if constexpr (A==4) return tanhf(v);                  // tanh
  else return v;
}

// ---------------------------------------------------------------------------
// Implicit-GEMM conv via mfma_f32_16x16x32_bf16.
// NCHW, stride 1, pad KK/2. Up to 4 concatenated sources.
// dt: 0=f32, 1=bf16, 2=warp-virtual (bilinear sample of net(f32,16ch) by flows)
// Block 256 thr = 4 waves. Output tile 16x16 px. M=pixel-in-row (16), rows=m-tiles.
// K = Cin (16-ch groups) x KK*KK taps, taken 2 taps per MFMA (K=32=16ci*2taps).
// NT = number of 16-co n-tiles (Cout <= NT*16).
// Frag layouts (gfx950, verified learn_hip m89/m92/m97):
//   A[m][k]: m=lane&15, k=(lane>>4)*8+j (8 contiguous bf16 = 1 b128)
//   B[k][n]: n=lane&15, k=(lane>>4)*8+j
//   D[row][col]: row=(lane>>4)*4+reg, col=lane&15
// k mapping: k&15 = ci-in-group, k>>4 = tap half -> off = 2p + (k>>4)
// ---------------------------------------------------------------------------
template<int KK, int ACT, int NT>
__global__ __launch_bounds__(256) void conv_mfma(
    const void* __restrict__ s0, int c0, int d0,
    const void* __restrict__ s1, int c1, int d1,
    const void* __restrict__ s2, int c2, int d2,
    const void* __restrict__ s3, int c3, int d3,
    const bf16* __restrict__ flows,
    const float* __restrict__ Wt, const float* __restrict__ bias,
    void* __restrict__ out, int outf32, int Cout, int Cstride,
    int H, int W)
{
  constexpr int TS = 16, HALO = TS + KK - 1, PAD = KK/2;
  constexpr int NPAIR = (KK*KK + 1)/2;
  constexpr int CPAD = 24;                       // bf16 slots per pixel (48B stride)
  constexpr int NMT = (NT==1) ? 4 : ((NT==2) ? 8 : 16);
  __shared__ __align__(16) bf16 As[HALO*HALO*CPAD];
  __shared__ __align__(16) bf16 Bs[NPAIR*NT*512];

  const int tid = threadIdx.x;
  const int lane = tid & 63, wv = tid >> 6;
  const int tilesx = W / TS;
  const int tx0 = (blockIdx.x % tilesx)*TS, ty0 = (blockIdx.x / tilesx)*TS;
  const int b = blockIdx.z;
  const int Cin = c0 + c1 + c2 + c3;
  const int HW = H*W;
  const int ngroups = (Cin + 15) >> 4;

  int ntile, mt0;
  if constexpr (NT==1)      { ntile = 0;     mt0 = wv*4; }
  else if constexpr (NT==2) { ntile = wv&1;  mt0 = (wv>>1)*8; }
  else                      { ntile = wv;    mt0 = 0; }

  f32x4 acc[NMT];
  #pragma unroll
  for (int t = 0; t < NMT; ++t) acc[t] = (f32x4){0.f,0.f,0.f,0.f};

  const int ln = lane & 15, gq = lane >> 4;

  for (int g16 = 0; g16 < ngroups; ++g16) {
    // ---- resolve the 16 channels of this group (uniform, in regs) ----
    const char* aptr[16]; int adt[16];
    bool virt = false; int vl = 0;
    #pragma unroll
    for (int ci = 0; ci < 16; ++ci) {
      const int cg = g16*16 + ci;
      const void* sp; int cl, dt, cN;
      if (cg >= Cin)            { sp=nullptr; cl=0; dt=-1; cN=1; }
      else if (cg < c0)         { sp=s0; cl=cg;          dt=d0; cN=c0; }
      else if (cg < c0+c1)      { sp=s1; cl=cg-c0;       dt=d1; cN=c1; }
      else if (cg < c0+c1+c2)   { sp=s2; cl=cg-c0-c1;    dt=d2; cN=c2; }
      else                      { sp=s3; cl=cg-c0-c1-c2; dt=d3; cN=c3; }
      if (dt == 2) {
        virt = true; vl = cl >> 4;
        aptr[ci] = (const char*)((const float*)sp + ((size_t)b*16 + (cl & 15))*(size_t)HW);
        adt[ci] = 0;  // gathered as f32
      } else if (dt == 1) {
        aptr[ci] = (const char*)((const bf16*)sp + ((size_t)b*cN + cl)*(size_t)HW); adt[ci]=1;
      } else if (dt == 0) {
        aptr[ci] = (const char*)((const float*)sp + ((size_t)b*cN + cl)*(size_t)HW); adt[ci]=0;
      } else { aptr[ci] = nullptr; adt[ci] = -1; }
    }

    // ---- stage A tile (halo, 16 ci interleaved per pixel) ----
    const bf16* fxp = nullptr; const bf16* fyp = nullptr;
    if (virt) { fxp = flows + ((size_t)b*8 + 2*vl)*(size_t)HW; fyp = fxp + HW; }
    for (int i = tid; i < HALO*HALO; i += 256) {
      const int hy = i / HALO, hx = i - hy*HALO;
      const int gy = ty0 + hy - PAD, gx = tx0 + hx - PAD;
      const bool inb = (gy >= 0 && gy < H && gx >= 0 && gx < W);
      __align__(16) bf16 vals[16];
      if (virt) {
        float w00=0.f, w10=0.f, w01=0.f, w11=0.f;
        size_t o00=0, o10=0, o01=0, o11=0;
        if (inb) {
          const size_t p = (size_t)gy*W + gx;
          const float fx = b2f(fxp[p]), fy = b2f(fyp[p]);
          const float vgx = (float)gx - fx, vgy = (float)gy - fy;
          const float gxn = 2.f*vgx/(float)(W-1) - 1.f;
          const float gyn = 2.f*vgy/(float)(H-1) - 1.f;
          const float ix = ((gxn+1.f)*(float)W - 1.f)*0.5f;
          const float iy = ((gyn+1.f)*(float)H - 1.f)*0.5f;
          const float x0f = floorf(ix), y0f = floorf(iy);
          const float wx1 = ix - x0f, wy1 = iy - y0f;
          const float wx0 = 1.f - wx1, wy0 = 1.f - wy1;
          const int x0 = (int)x0f, y0 = (int)y0f, x1 = x0+1, y1 = y0+1;
          const bool vx0 = (x0>=0)&(x0<W), vx1 = (x1>=0)&(x1<W);
          const bool vy0 = (y0>=0)&(y0<H), vy1 = (y1>=0)&(y1<H);
          const int xc0 = min(max(x0,0),W-1), xc1 = min(max(x1,0),W-1);
          const int yc0 = min(max(y0,0),H-1), yc1 = min(max(y1,0),H-1);
          w00 = wx0*wy0*((vx0&&vy0)?1.f:0.f);
          w10 = wx1*wy0*((vx1&&vy0)?1.f:0.f);
          w01 = wx0*wy1*((vx0&&vy1)?1.f:0.f);
          w11 = wx1*wy1*((vx1&&vy1)?1.f:0.f);
          o00 = (size_t)yc0*W+xc0; o10 = (size_t)yc0*W+xc1;
          o01 = (size_t)yc1*W+xc0; o11 = (size_t)yc1*W+xc1;
        }
        #pragma unroll
        for (int ci = 0; ci < 16; ++ci) {
          float v = 0.f;
          if (inb) {
            const float* np = (const float*)aptr[ci];
            v = w00*np[o00] + w10*np[o10] + w01*np[o01] + w11*np[o11];
          }
          vals[ci] = f2b(v);
        }
      } else {
        const size_t idx = inb ? ((size_t)gy*W + gx) : 0;
        #pragma unroll
        for (int ci = 0; ci < 16; ++ci) {
          float v = 0.f;
          if (inb && adt[ci] >= 0)
            v = (adt[ci]==1) ? b2f(((const bf16*)aptr[ci])[idx])
                             : ((const float*)aptr[ci])[idx];
          vals[ci] = f2b(v);
        }
      }
      *(float4*)(As + (size_t)i*CPAD)     = *(const float4*)&vals[0];
      *(float4*)(As + (size_t)i*CPAD + 8) = *(const float4*)&vals[8];
    }

    // ---- stage B (weights) for all pairs of this group: [p][nt][n][k] ----
    for (int i = tid; i < NPAIR*NT*512; i += 256) {
      const int k = i & 31, n = (i >> 5) & 15, pnt = i >> 9;
      const int p = pnt / NT, nt = pnt - p*NT;
      const int off = 2*p + (k >> 4);
      const int co = nt*16 + n, cig = g16*16 + (k & 15);
      float wgt = 0.f;
      if (off < KK*KK && co < Cout && cig < Cin)
        wgt = Wt[((size_t)co*Cin + cig)*(KK*KK) + off];
      Bs[i] = f2b(wgt);
    }
    __syncthreads();

    // ---- MFMA phase ----
    const char* Asb = (const char*)As;
    const char* Bsb = (const char*)Bs;
    #pragma unroll
    for (int p = 0; p < NPAIR; ++p) {
      const short8 bfrag = *(const short8*)(Bsb + ((p*NT + ntile) << 10) + (ln << 6) + (gq << 4));
      int off = 2*p + (gq >> 1);
      if (off >= KK*KK) off = 0;                  // pad half: B is zero there
      const int dy = off / KK, dx = off - (off/KK)*KK;
      const int colb = (ln + dx)*48 + ((gq & 1) << 4);
      #pragma unroll
      for (int t = 0; t < NMT; ++t) {
        const int P = (mt0 + t + dy)*HALO;
        const short8 afrag = *(const short8*)(Asb + P*48 + colb);
        acc[t] = __builtin_amdgcn_mfma_f32_16x16x32_bf16(afrag, bfrag, acc[t], 0, 0, 0);
      }
    }
    __syncthreads();
  }

  // ---- epilogue: bias + activation + store ----
  const int co = ntile*16 + ln;
  if (co < Cout) {
    const float bv = bias ? bias[co] : 0.f;
    #pragma unroll
    for (int t = 0; t < NMT; ++t) {
      const int oy = ty0 + mt0 + t, ox = tx0 + gq*4;
      const size_t o = ((size_t)b*Cstride + co)*(size_t)HW + (size_t)oy*W + ox;
      float v0 = act_fn<ACT>(acc[t][0] + bv);
      float v1 = act_fn<ACT>(acc[t][1] + bv);
      float v2 = act_fn<ACT>(acc[t][2] + bv);
      float v3 = act_fn<ACT>(acc[t][3] + bv);
      if (outf32) {
        float4 f; f.x=v0; f.y=v1; f.z=v2; f.w=v3;
        *(float4*)((float*)out + o) = f;
      } else {
        __align__(8) bf16 tmp[4];
        tmp[0]=f2b(v0); tmp[1]=f2b(v1); tmp[2]=f2b(v2); tmp[3]=f2b(v3);
        *(uint2*)((bf16*)out + o) = *(const uint2*)tmp;
      }
    }
  }
}

// concat [wz|wr] weights and [bz|br] bias
__global__ void concat_zr(const float* __restrict__ wz, const float* __restrict__ wr,
                          const float* __restrict__ bz, const float* __restrict__ br,
                          float* __restrict__ wzr, float* __restrict__ bzr){
  const int n = 16*144*9;
  const int i = blockIdx.x*256 + threadIdx.x;
  if (i < n) { wzr[i] = wz[i]; wzr[n+i] = wr[i]; }
  if (i < 16) { bzr[i] = bz[i]; bzr[16+i] = br[i]; }
}

// rh = rg * net   (rg = channels 16..31 of zgrg)
__global__ void rh_kernel(const bf16* __restrict__ zgrg, const float* __restrict__ net,
                          bf16* __restrict__ rh, int HW){
  const int i = blockIdx.x*256 + threadIdx.x;
  const int c = blockIdx.y, b = blockIdx.z;
  if (i >= HW) return;
  const float rg = b2f(zgrg[((size_t)b*32 + 16 + c)*(size_t)HW + i]);
  const size_t o = ((size_t)b*16 + c)*(size_t)HW + i;
  rh[o] = f2b(rg * net[o]);
}

// h1 = (1-zg)*net + zg*q   (zg = channels 0..15 of zgrg), written f32 to d_out
__global__ void h1_kernel(const bf16* __restrict__ zgrg, const bf16* __restrict__ q,
                          const float* __restrict__ net, float* __restrict__ h1, int HW){
  const int i = blockIdx.x*256 + threadIdx.x;
  const int c = blockIdx.y, b = blockIdx.z;
  if (i >= HW) return;
  const float z = b2f(zgrg[((size_t)b*32 + c)*(size_t)HW + i]);
  const size_t o = ((size_t)b*16 + c)*(size_t)HW + i;
  h1[o] = (1.f - z)*net[o] + z*b2f(q[o]);
}

// per-(b,c) mean & max over HW
__global__ __launch_bounds__(256) void castats_kernel(const float* __restrict__ h1,
                                                      float* __restrict__ stats, int HW){
  const int bc = blockIdx.x;
  const float* p = h1 + (size_t)bc*(size_t)HW;
  float s = 0.f, m = -3.4e38f;
  for (int i = threadIdx.x; i < HW; i += 256) { const float v = p[i]; s += v; m = fmaxf(m, v); }
  #pragma unroll
  for (int o = 32; o >= 1; o >>= 1) { s += __shfl_down(s, o); m = fmaxf(m, __shfl_down(m, o)); }
  __shared__ float ss[4], sm[4];
  const int wave = threadIdx.x >> 6;
  if ((threadIdx.x & 63) == 0) { ss[wave] = s; sm[wave] = m; }
  __syncthreads();
  if (threadIdx.x == 0) {
    const float S = ss[0]+ss[1]+ss[2]+ss[3];
    const float M = fmaxf(fmaxf(sm[0],sm[1]), fmaxf(sm[2],sm[3]));
    stats[bc*2] = S/(float)HW; stats[bc*2+1] = M;
  }
}

// channel-attention scale
__global__ void cascale_kernel(const float* __restrict__ stats, const float* __restrict__ w1,
                               const float* __restrict__ w2, float* __restrict__ scale){
  const int t = threadIdx.x;       // 64 = 4b x 16c
  const int c = t & 15;
  float pa = w1[c]*stats[t*2], pm = w1[c]*stats[t*2+1];
  #pragma unroll
  for (int o = 8; o >= 1; o >>= 1) { pa += __shfl_xor(pa, o, 16); pm += __shfl_xor(pm, o, 16); }
  const float y = w2[c]*fmaxf(pa, 0.f) + w2[c]*fmaxf(pm, 0.f);
  scale[t] = 1.f/(1.f+expf(-y));
}

// per-pixel mean/max over 16 channels of h1*scale
__global__ void sastats_kernel(const float* __restrict__ h1, const float* __restrict__ scale,
                               bf16* __restrict__ sa2, int HW){
  const int i = blockIdx.x*256 + threadIdx.x;
  const int b = blockIdx.y;
  if (i >= HW) return;
  float s = 0.f, m = -3.4e38f;
  #pragma unroll
  for (int c = 0; c < 16; ++c) {
    const float v = h1[((size_t)b*16 + c)*(size_t)HW + i]*scale[b*16+c];
    s += v; m = fmaxf(m, v);
  }
  sa2[((size_t)b*2 + 0)*(size_t)HW + i] = f2b(s*(1.f/16.f));
  sa2[((size_t)b*2 + 1)*(size_t)HW + i] = f2b(m);
}

// 7x7 conv 2ch->1, pad 3, no bias, fused sigmoid
__global__ __launch_bounds__(256) void saconv_kernel(const bf16* __restrict__ sa2,
    const float* __restrict__ w, bf16* __restrict__ samap, int H, int W){
  __shared__ float wl[98];
  if (threadIdx.x < 98) wl[threadIdx.x] = w[threadIdx.x];
  __syncthreads();
  const int i = blockIdx.x*256 + threadIdx.x;
  const int b = blockIdx.y;
  const int HW = H*W;
  if (i >= HW) return;
  const int y = i / W, x = i - (i / W)*W;
  float s = 0.f;
  #pragma unroll
  for (int ch = 0; ch < 2; ++ch) {
    const size_t base = ((size_t)b*2 + ch)*(size_t)HW;
    for (int ky = 0; ky < 7; ++ky) {
      const int yy = y + ky - 3;
      if (yy < 0 || yy >= H) continue;
      for (int kx = 0; kx < 7; ++kx) {
        const int xx = x + kx - 3;
        if (xx < 0 || xx >= W) continue;
        s += b2f(sa2[base + (size_t)yy*W + xx]) * wl[ch*49 + ky*7 + kx];
      }
    }
  }
  samap[(size_t)b*(size_t)HW + i] = f2b(1.f/(1.f+expf(-s)));
}

// out_h *= scale * samap  (in place on d_out)
__global__ void hfinal_kernel(float* __restrict__ outh, const float* __restrict__ scale,
                              const bf16* __restrict__ samap, int HW){
  const int i = blockIdx.x*256 + threadIdx.x;
  const int b = blockIdx.y;
  if (i >= HW) return;
  const float sa = b2f(samap[(size_t)b*(size_t)HW + i]);
  #pragma unroll
  for (int c = 0; c < 16; ++c) {
    const size_t o = ((size_t)b*16 + c)*(size_t)HW + i;
    outh[o] = outh[o]*scale[b*16+c]*sa;
  }
}

struct Src { const void* p; int c; int dt; };

extern "C" void kernel_launch(void* const* d_in, const int* in_sizes, int n_in,
                              void* d_out, int out_size, void* d_ws, size_t ws_size,
                              hipStream_t stream)
{
  const float* net   = (const float*)d_in[0];
  const float* inp   = (const float*)d_in[1];
  const float* corr  = (const float*)d_in[2];
  const float* noise = (const float*)d_in[3];
  const float* wc1 = (const float*)d_in[4];  const float* bc1 = (const float*)d_in[5];
  const float* wc2 = (const float*)d_in[6];  const float* bc2 = (const float*)d_in[7];
  const float* wf1 = (const float*)d_in[8];  const float* bf1 = (const float*)d_in[9];
  const float* wf2 = (const float*)d_in[10]; const float* bf2 = (const float*)d_in[11];
  const float* we  = (const float*)d_in[12]; const float* be  = (const float*)d_in[13];
  const float* loc1_w = (const float*)d_in[14]; const float* loc1_b = (const float*)d_in[15];
  const float* loc2_w = (const float*)d_in[16]; const float* loc2_b = (const float*)d_in[17];
  const float* wz = (const float*)d_in[18]; const float* bz = (const float*)d_in[19];
  const float* wr = (const float*)d_in[20]; const float* br = (const float*)d_in[21];
  const float* wq = (const float*)d_in[22]; const float* bq = (const float*)d_in[23];
  const float* ca_w1 = (const float*)d_in[24]; const float* ca_w2 = (const float*)d_in[25];
  const float* sa_w  = (const float*)d_in[26];
  const float* fh1_w = (const float*)d_in[27]; const float* fh1_b = (const float*)d_in[28];
  const float* fh2_w = (const float*)d_in[29]; const float* fh2_b = (const float*)d_in[30];

  const int B = 4, H = 512, W = 512, HW = H*W;
  char* ws = (char*)d_ws;
  const size_t MB = 1ull << 20;
  // Workspace [0,256MB), same (verified) plan as round 2:
  //   M [0,128):   flo1 (transient) -> mo (61ch) -> CBAM smalls -> fh1o
  //   A [128,192): cor1 -> flo2 -> t -> zgrg(32ch, 64MB)
  //   C [192,256): cor2 -> flows -> rh | q
  bf16* mo    = (bf16*)(ws);
  bf16* flo1  = (bf16*)(ws);
  bf16* cor1  = (bf16*)(ws + 128*MB);
  bf16* flo2  = (bf16*)(ws + 128*MB);
  bf16* t     = (bf16*)(ws + 128*MB);
  bf16* zgrg  = (bf16*)(ws + 128*MB);
  bf16* cor2  = (bf16*)(ws + 192*MB);
  bf16* flows = (bf16*)(ws + 192*MB);
  bf16* rh    = (bf16*)(ws + 192*MB);
  bf16* q     = (bf16*)(ws + 224*MB);
  bf16* fh1o  = (bf16*)(ws);
  float* stats= (float*)(ws);
  float* scale= (float*)(ws + 64*1024);
  bf16* sa2   = (bf16*)(ws + 1*MB);
  bf16* samap = (bf16*)(ws + 5*MB);

  float* out_h  = (float*)d_out;
  float* out_df = out_h + (size_t)B*16*HW;
  float* wzr = out_df;                       // parked in not-yet-written df region
  float* bzr = wzr + 2*16*144*9;

  const dim3 cgrid((W/16)*(H/16), 1, B);
  Src NONE{nullptr,0,0};

  #define CONV(KK,ACT,NT, A_,B_,C_,D_, FL, WT, BI, OUT, OF32, COUT, CS) \
    conv_mfma<KK,ACT,NT><<<cgrid,256,0,stream>>>( \
      A_.p,A_.c,A_.dt, B_.p,B_.c,B_.dt, C_.p,C_.c,C_.dt, D_.p,D_.c,D_.dt, \
      FL, WT, BI, OUT, OF32, COUT, CS, H, W)

  concat_zr<<<(16*144*9 + 255)/256, 256, 0, stream>>>(wz, wr, bz, br, wzr, bzr);

  // --- BasicMotionEncoder ---
  { Src a{corr,3,0};  CONV(3,1,2, a,NONE,NONE,NONE, nullptr, wc1,bc1, cor1,0, 32,32); }
  { Src a{cor1,32,1}; CONV(3,1,2, a,NONE,NONE,NONE, nullptr, wc2,bc2, cor2,0, 32,32); }
  { Src a{noise,3,0}; CONV(3,1,2, a,NONE,NONE,NONE, nullptr, wf1,bf1, flo1,0, 32,32); }
  { Src a{flo1,32,1}; CONV(3,1,2, a,NONE,NONE,NONE, nullptr, wf2,bf2, flo2,0, 32,32); }
  { Src a{cor2,32,1}, b{flo2,32,1};
    CONV(3,1,4, a,b,NONE,NONE, nullptr, we,be, mo,0, 61,61); }

  // --- local flows ---
  { Src a{inp,16,0}, b{mo,61,1}, c{noise,3,0}, d{net,16,0};
    CONV(5,2,1, a,b,c,d, nullptr, loc1_w,loc1_b, t,0, 16,16); }
  { Src a{t,16,1};    CONV(5,0,1, a,NONE,NONE,NONE, nullptr, loc2_w,loc2_b, flows,0, 8,8); }

  // --- GRU (warp fused into staging via dt=2 virtual source) ---
  { Src a{net,64,2}, b{inp,16,0}, c{mo,61,1}, d{noise,3,0};
    CONV(3,3,2, a,b,c,d, flows, wzr,bzr, zgrg,0, 32,32); }
  rh_kernel<<<dim3(HW/256,16,B),256,0,stream>>>(zgrg, net, rh, HW);
  { Src a{rh,16,1}, b{inp,16,0}, c{mo,61,1}, d{noise,3,0};
    CONV(3,4,1, a,b,c,d, nullptr, wq,bq, q,0, 16,16); }
  h1_kernel<<<dim3(HW/256,16,B),256,0,stream>>>(zgrg, q, net, out_h, HW);

  // --- CBAM ---
  castats_kernel<<<64,256,0,stream>>>(out_h, stats, HW);
  cascale_kernel<<<1,64,0,stream>>>(stats, ca_w1, ca_w2, scale);
  sastats_kernel<<<dim3(HW/256,B),256,0,stream>>>(out_h, scale, sa2, HW);
  saconv_kernel<<<dim3(HW/256,B),256,0,stream>>>(sa2, sa_w, samap, H, W);
  hfinal_kernel<<<dim3(HW/256,B),256,0,stream>>>(out_h, scale, samap, HW);

  // --- FlowHead ---
  { Src a{out_h,16,0}; CONV(3,1,4, a,NONE,NONE,NONE, nullptr, fh1_w,fh1_b, fh1o,0, 64,64); }
  { Src a{fh1o,64,1};  CONV(3,0,1, a,NONE,NONE,NONE, nullptr, fh2_w,fh2_b, out_df,1, 3,3); }

  #undef CONV
}

// Round 4
// 1036.023 us; speedup vs baseline: 8.0500x; 3.2595x over previous
//
#include <hip/hip_runtime.h>
#include <hip/hip_bf16.h>
#include <math.h>

using bf16 = __hip_bfloat16;
typedef __attribute__((ext_vector_type(8))) short short8;
typedef __attribute__((ext_vector_type(4))) float f32x4;

__device__ __forceinline__ float b2f(bf16 v){ return __bfloat162float(v); }
__device__ __forceinline__ bf16 f2b(float v){ return __float2bfloat16(v); }
__device__ __forceinline__ float bs2f(short s){
  union{unsigned u; float f;} x; x.u = ((unsigned)(unsigned short)s)<<16; return x.f;
}

template<int A> __device__ __forceinline__ float act_fn(float v){
  if constexpr (A==1) return fmaxf(v, 0.f);
  else if constexpr (A==2) return v > 0.f ? v : 0.2f*v;
  else if constexpr (A==3) return 1.f/(1.f+expf(-v));
  else if constexpr (A==4) return tanhf(v);
  else return v;
}

struct Srcs9 { const bf16* p[9]; int code[9]; };   // code 0=plain slab, 1+l = warp-virtual layer l
struct WMap  { int base[9]; int lo[9]; int hi[9]; };

// ---------------------------------------------------------------------------
// Implicit-GEMM conv via mfma_f32_16x16x32_bf16, slab16 inputs/outputs.
// A-frag: m=lane&15 (x-in-tile), k=(lane>>4)*8+j ; B-frag: n=lane&15, same k
// D: row=(lane>>4)*4+reg = m, col=lane&15 = n   (verified layout, round 3)
// k&15 = ci within 16-ch group, k>>4 = tap parity; off = 2p + (k>>4)
// B read directly from global in prepass layout: elem ((g*NPAIR+p)*NT+nt)*512 + lane*8
// ---------------------------------------------------------------------------
template<int KK, int ACT, int NT>
__global__ __launch_bounds__(256) void conv_mfma(
    Srcs9 S, int Gin, const bf16* __restrict__ flows,
    const bf16* __restrict__ Bw, const float* __restrict__ bias,
    bf16* __restrict__ outS, size_t slabS, float* __restrict__ outF, int Cout,
    int H, int W)
{
  constexpr int TS=16, HALO=TS+KK-1, PAD=KK/2, NPAIR=(KK*KK+1)/2, HH=HALO*HALO;
  constexpr int NMT = (NT==1)?4:((NT==2)?8:16);
  __shared__ __align__(16) bf16 As[2][HH*24];
  const int tid=threadIdx.x, lane=tid&63, wv=tid>>6;
  const int ln=lane&15, gq=lane>>4;
  const int tilesx=W/TS;
  const int tx0=(blockIdx.x%tilesx)*TS, ty0=(blockIdx.x/tilesx)*TS;
  const int b=blockIdx.z; const int HW=H*W;
  int ntile, mt0;
  if constexpr (NT==1){ ntile=0;    mt0=wv*4; }
  else if constexpr (NT==2){ ntile=wv&1; mt0=(wv>>1)*8; }
  else { ntile=wv; mt0=0; }

  f32x4 acc[NMT];
  #pragma unroll
  for (int t=0;t<NMT;++t) acc[t]=(f32x4){0.f,0.f,0.f,0.f};

  const short8 Z8 = {0,0,0,0,0,0,0,0};
  const int px0=tid, px1=tid+256;
  const int hy0=px0/HALO, hx0=px0-hy0*HALO;
  const int hy1=px1/HALO, hx1=px1-hy1*HALO;
  const bool act1 = (px1<HH);
  const int gy0=ty0+hy0-PAD, gx0=tx0+hx0-PAD;
  const int gy1=ty0+hy1-PAD, gx1=tx0+hx1-PAD;
  const bool in0 = (gy0>=0&&gy0<H&&gx0>=0&&gx0<W);
  const bool in1 = act1 && (gy1>=0&&gy1<H&&gx1>=0&&gx1<W);

  auto gather = [&](int g, bool inb, int gy, int gx, short8& A0, short8& A1){
    const int code = S.code[g];
    const bf16* sp = S.p[g];
    if (code == 0) {
      if (inb) {
        const bf16* qp = sp + ((size_t)b*HW + (size_t)gy*W + gx)*16;
        A0 = *(const short8*)qp; A1 = *(const short8*)(qp+8);
      } else { A0 = Z8; A1 = Z8; }
    } else {
      if (inb) {
        const int l = code-1;
        const size_t p = (size_t)b*HW + (size_t)gy*W + gx;
        const unsigned fp_ = *(const unsigned*)(flows + p*16 + 2*l);
        const float fx = bs2f((short)(fp_&0xffff)), fy = bs2f((short)(fp_>>16));
        const float vgx = (float)gx - fx, vgy = (float)gy - fy;
        const float gxn = 2.f*vgx/(float)(W-1) - 1.f;
        const float gyn = 2.f*vgy/(float)(H-1) - 1.f;
        const float ix = ((gxn+1.f)*(float)W - 1.f)*0.5f;
        const float iy = ((gyn+1.f)*(float)H - 1.f)*0.5f;
        const float x0f = floorf(ix), y0f = floorf(iy);
        const float wx1 = ix-x0f, wy1 = iy-y0f, wx0 = 1.f-wx1, wy0 = 1.f-wy1;
        const int x0=(int)x0f, y0=(int)y0f, x1=x0+1, y1=y0+1;
        const bool vx0=(x0>=0)&(x0<W), vx1=(x1>=0)&(x1<W);
        const bool vy0=(y0>=0)&(y0<H), vy1=(y1>=0)&(y1<H);
        const int xc0=min(max(x0,0),W-1), xc1=min(max(x1,0),W-1);
        const int yc0=min(max(y0,0),H-1), yc1=min(max(y1,0),H-1);
        const float w00=wx0*wy0*((vx0&&vy0)?1.f:0.f);
        const float w10=wx1*wy0*((vx1&&vy0)?1.f:0.f);
        const float w01=wx0*wy1*((vx0&&vy1)?1.f:0.f);
        const float w11=wx1*wy1*((vx1&&vy1)?1.f:0.f);
        const bf16* nb = sp + (size_t)b*HW*16;
        const bf16* p00 = nb + ((size_t)yc0*W+xc0)*16;
        const bf16* p10 = nb + ((size_t)yc0*W+xc1)*16;
        const bf16* p01 = nb + ((size_t)yc1*W+xc0)*16;
        const bf16* p11 = nb + ((size_t)yc1*W+xc1)*16;
        const short8 a00=*(const short8*)p00, b00=*(const short8*)(p00+8);
        const short8 a10=*(const short8*)p10, b10=*(const short8*)(p10+8);
        const short8 a01=*(const short8*)p01, b01=*(const short8*)(p01+8);
        const short8 a11=*(const short8*)p11, b11=*(const short8*)(p11+8);
        __align__(16) bf16 tmp[16];
        #pragma unroll
        for (int c=0;c<8;++c){
          tmp[c]   = f2b(w00*bs2f(a00[c]) + w10*bs2f(a10[c]) + w01*bs2f(a01[c]) + w11*bs2f(a11[c]));
          tmp[8+c] = f2b(w00*bs2f(b00[c]) + w10*bs2f(b10[c]) + w01*bs2f(b01[c]) + w11*bs2f(b11[c]));
        }
        A0 = *(const short8*)tmp; A1 = *(const short8*)(tmp+8);
      } else { A0 = Z8; A1 = Z8; }
    }
  };

  auto mfma_g = [&](int g, const bf16* buf){
    #pragma unroll
    for (int p=0;p<NPAIR;++p){
      const short8 bfrag = *(const short8*)(Bw + ((((size_t)g*NPAIR+p)*NT + ntile)*64 + lane)*8);
      int off = 2*p + (gq>>1);
      if (off >= KK*KK) off = 0;               // pad tap: B is zero there
      const int dy = off/KK, dx = off - (off/KK)*KK;
      const int ce = (ln+dx)*24 + ((gq&1)*8);
      #pragma unroll
      for (int t=0;t<NMT;++t){
        const short8 af = *(const short8*)(buf + (size_t)(mt0+t+dy)*HALO*24 + ce);
        acc[t] = __builtin_amdgcn_mfma_f32_16x16x32_bf16(af, bfrag, acc[t], 0, 0, 0);
      }
    }
  };

  for (int g=0; g<Gin; ++g) {
    short8 a0, a1, c0v, c1v;
    gather(g, in0, gy0, gx0, a0, a1);
    if (act1) gather(g, in1, gy1, gx1, c0v, c1v);
    if (g > 0) mfma_g(g-1, As[(g-1)&1]);
    bf16* buf = As[g&1];
    *(short8*)(buf + (size_t)px0*24)     = a0;
    *(short8*)(buf + (size_t)px0*24 + 8) = a1;
    if (act1){
      *(short8*)(buf + (size_t)px1*24)     = c0v;
      *(short8*)(buf + (size_t)px1*24 + 8) = c1v;
    }
    __syncthreads();
  }
  mfma_g(Gin-1, As[(Gin-1)&1]);

  // ---- epilogue ----
  const int co = ntile*16 + ln;
  const float bv = bias[co];
  if (outS) {
    #pragma unroll
    for (int t=0;t<NMT;++t){
      const int y = ty0 + mt0 + t;
      bf16* op = outS + (size_t)ntile*slabS + ((size_t)b*HW + (size_t)y*W + tx0 + gq*4)*16 + ln;
      #pragma unroll
      for (int r=0;r<4;++r) op[(size_t)r*16] = f2b(act_fn<ACT>(acc[t][r] + bv));
    }
  } else {
    if (co < Cout) {
      #pragma unroll
      for (int t=0;t<NMT;++t){
        const int y = ty0 + mt0 + t;
        float4 f;
        f.x = act_fn<ACT>(acc[t][0]+bv); f.y = act_fn<ACT>(acc[t][1]+bv);
        f.z = act_fn<ACT>(acc[t][2]+bv); f.w = act_fn<ACT>(acc[t][3]+bv);
        *(float4*)(outF + ((size_t)b*Cout + co)*HW + (size_t)y*W + tx0 + gq*4) = f;
      }
    }
  }
}

// ---- weight prepass: f32 OIHW -> bf16 MFMA B-fragment order ----
__global__ void prep_w(const float* __restrict__ W1, const float* __restrict__ W2, int coSplit,
                       const float* __restrict__ b1, const float* __restrict__ b2,
                       WMap M, int NPAIR, int NTp, int Cout, int CinO, int T,
                       bf16* __restrict__ Bw, float* __restrict__ bOut, int total)
{
  const int i = blockIdx.x*256 + threadIdx.x;
  if (i < total) {
    const int j=i&7, l=(i>>3)&63, ln2=l&15, gq2=l>>4;
    int r=i>>9; const int nt=r%NTp; r/=NTp; const int p=r%NPAIR; const int g=r/NPAIR;
    const int k=gq2*8+j, off=2*p+(k>>4), ci=k&15, co=nt*16+ln2;
    float w=0.f;
    if (off<T && co<Cout && ci>=M.lo[g] && ci<M.hi[g]) {
      const int cin = M.base[g]+ci;
      if (!W2 || co<coSplit) w = W1[((size_t)co*CinO+cin)*T+off];
      else                   w = W2[((size_t)(co-coSplit)*CinO+cin)*T+off];
    }
    Bw[i] = f2b(w);
  }
  if (i < 64) {
    float bv=0.f;
    if (i<Cout) bv = (!b2 || i<coSplit) ? (b1? b1[i]:0.f) : b2[i-coSplit];
    bOut[i]=bv;
  }
}

// ---- pack f32 NCHW 16ch -> slab16 bf16 ----
__global__ void pack16(const float* __restrict__ src, bf16* __restrict__ dst, int HW){
  const int px = blockIdx.x*256+threadIdx.x; const int b=blockIdx.y;
  if (px>=HW) return;
  __align__(16) bf16 t[16];
  #pragma unroll
  for (int c=0;c<16;++c) t[c]=f2b(src[((size_t)b*16+c)*HW+px]);
  bf16* d = dst + ((size_t)b*HW+px)*16;
  *(short8*)d = *(const short8*)t; *(short8*)(d+8) = *(const short8*)(t+8);
}

__global__ void pack_cn(const float* __restrict__ corr, const float* __restrict__ noise,
                        bf16* __restrict__ dst, int HW){
  const int px = blockIdx.x*256+threadIdx.x; const int b=blockIdx.y;
  if (px>=HW) return;
  __align__(16) bf16 t[16];
  #pragma unroll
  for (int c=0;c<16;++c) t[c]=f2b(0.f);
  #pragma unroll
  for (int c=0;c<3;++c){
    t[c]   = f2b(corr [((size_t)b*3+c)*HW+px]);
    t[3+c] = f2b(noise[((size_t)b*3+c)*HW+px]);
  }
  bf16* d = dst + ((size_t)b*HW+px)*16;
  *(short8*)d = *(const short8*)t; *(short8*)(d+8) = *(const short8*)(t+8);
}

__global__ void noise_tail(const float* __restrict__ noise, bf16* __restrict__ mslab3, int HW){
  const int px = blockIdx.x*256+threadIdx.x; const int b=blockIdx.y;
  if (px>=HW) return;
  bf16* d = mslab3 + ((size_t)b*HW+px)*16;
  #pragma unroll
  for (int c=0;c<3;++c) d[13+c] = f2b(noise[((size_t)b*3+c)*HW+px]);
}

__global__ void rh_k(const bf16* __restrict__ rg, const bf16* __restrict__ netT,
                     bf16* __restrict__ rh, int HW){
  const int px = blockIdx.x*256+threadIdx.x; const int b=blockIdx.y;
  if (px>=HW) return;
  const size_t base = ((size_t)b*HW+px)*16;
  const short8 r0=*(const short8*)(rg+base),  r1=*(const short8*)(rg+base+8);
  const short8 n0=*(const short8*)(netT+base), n1=*(const short8*)(netT+base+8);
  __align__(16) bf16 t[16];
  #pragma unroll
  for (int c=0;c<8;++c){
    t[c]   = f2b(bs2f(r0[c])*bs2f(n0[c]));
    t[8+c] = f2b(bs2f(r1[c])*bs2f(n1[c]));
  }
  *(short8*)(rh+base) = *(const short8*)t; *(short8*)(rh+base+8) = *(const short8*)(t+8);
}

__global__ void h1_k(const bf16* __restrict__ zg, const bf16* __restrict__ q,
                     const float* __restrict__ net, bf16* __restrict__ hT, int HW){
  const int px = blockIdx.x*256+threadIdx.x; const int b=blockIdx.y;
  if (px>=HW) return;
  const size_t base = ((size_t)b*HW+px)*16;
  const short8 z0=*(const short8*)(zg+base), z1=*(const short8*)(zg+base+8);
  const short8 q0=*(const short8*)(q+base),  q1=*(const short8*)(q+base+8);
  __align__(16) bf16 t[16];
  #pragma unroll
  for (int c=0;c<8;++c){
    const float za=bs2f(z0[c]), zb=bs2f(z1[c]);
    const float na=net[((size_t)b*16+c)*HW+px], nb2=net[((size_t)b*16+8+c)*HW+px];
    t[c]   = f2b((1.f-za)*na + za*bs2f(q0[c]));
    t[8+c] = f2b((1.f-zb)*nb2 + zb*bs2f(q1[c]));
  }
  *(short8*)(hT+base) = *(const short8*)t; *(short8*)(hT+base+8) = *(const short8*)(t+8);
}

__global__ __launch_bounds__(256) void castats_p1(const bf16* __restrict__ hT,
                                                  float* __restrict__ part, int HW){
  const int blk=blockIdx.x, b=blockIdx.y;
  const int per = HW>>5;
  const bf16* base = hT + ((size_t)b*HW + (size_t)blk*per)*16;
  float s[16], m[16];
  #pragma unroll
  for (int c=0;c<16;++c){ s[c]=0.f; m[c]=-3.4e38f; }
  for (int i=threadIdx.x;i<per;i+=256){
    const short8 a=*(const short8*)(base+(size_t)i*16);
    const short8 bb=*(const short8*)(base+(size_t)i*16+8);
    #pragma unroll
    for (int c=0;c<8;++c){
      const float v=bs2f(a[c]);  s[c]+=v;   m[c]=fmaxf(m[c],v);
      const float w=bs2f(bb[c]); s[8+c]+=w; m[8+c]=fmaxf(m[8+c],w);
    }
  }
  #pragma unroll
  for (int o=32;o>=1;o>>=1){
    #pragma unroll
    for (int c=0;c<16;++c){ s[c]+=__shfl_down(s[c],o); m[c]=fmaxf(m[c],__shfl_down(m[c],o)); }
  }
  __shared__ float ls[4][16], lm[4][16];
  const int w4=threadIdx.x>>6;
  if ((threadIdx.x&63)==0){
    #pragma unroll
    for (int c=0;c<16;++c){ ls[w4][c]=s[c]; lm[w4][c]=m[c]; }
  }
  __syncthreads();
  if (threadIdx.x<16){
    const int c=threadIdx.x;
    part[((size_t)(b*32+blk))*32 + c]      = ls[0][c]+ls[1][c]+ls[2][c]+ls[3][c];
    part[((size_t)(b*32+blk))*32 + 16 + c] = fmaxf(fmaxf(lm[0][c],lm[1][c]),fmaxf(lm[2][c],lm[3][c]));
  }
}

__global__ void castats_p2(const float* __restrict__ part, float* __restrict__ stats, int HW){
  const int t = threadIdx.x; if (t>=64) return;
  const int b=t>>4, c=t&15;
  float s=0.f, m=-3.4e38f;
  for (int k=0;k<32;++k){
    s += part[((size_t)(b*32+k))*32 + c];
    m  = fmaxf(m, part[((size_t)(b*32+k))*32 + 16 + c]);
  }
  stats[t*2]=s/(float)HW; stats[t*2+1]=m;
}

__global__ void cascale_k(const float* __restrict__ stats, const float* __restrict__ w1,
                          const float* __restrict__ w2, float* __restrict__ scale){
  const int t = threadIdx.x; if (t>=64) return;
  const int c = t & 15;
  float pa = w1[c]*stats[t*2], pm = w1[c]*stats[t*2+1];
  #pragma unroll
  for (int o=8;o>=1;o>>=1){ pa += __shfl_xor(pa,o,16); pm += __shfl_xor(pm,o,16); }
  const float y = w2[c]*fmaxf(pa,0.f) + w2[c]*fmaxf(pm,0.f);
  scale[t] = 1.f/(1.f+expf(-y));
}

__global__ void sastats_k(const bf16* __restrict__ hT, const float* __restrict__ scale,
                          bf16* __restrict__ sa2, int HW){
  const int px = blockIdx.x*256+threadIdx.x; const int b=blockIdx.y;
  if (px>=HW) return;
  const size_t base = ((size_t)b*HW+px)*16;
  const short8 a=*(const short8*)(hT+base), c8=*(const short8*)(hT+base+8);
  float s=0.f, m=-3.4e38f;
  #pragma unroll
  for (int c=0;c<8;++c){
    const float v=bs2f(a[c])*scale[b*16+c];    s+=v; m=fmaxf(m,v);
    const float w=bs2f(c8[c])*scale[b*16+8+c]; s+=w; m=fmaxf(m,w);
  }
  sa2[((size_t)b*2+0)*HW+px] = f2b(s*(1.f/16.f));
  sa2[((size_t)b*2+1)*HW+px] = f2b(m);
}

__global__ __launch_bounds__(256) void saconv_k(const bf16* __restrict__ sa2,
    const float* __restrict__ w, bf16* __restrict__ samap, int H, int W){
  __shared__ float wl[98];
  if (threadIdx.x < 98) wl[threadIdx.x] = w[threadIdx.x];
  __syncthreads();
  const int i = blockIdx.x*256 + threadIdx.x; const int b = blockIdx.y;
  const int HW = H*W;
  if (i >= HW) return;
  const int y = i / W, x = i - (i/W)*W;
  float s = 0.f;
  #pragma unroll
  for (int ch=0; ch<2; ++ch){
    const size_t base = ((size_t)b*2+ch)*HW;
    for (int ky=0;ky<7;++ky){
      const int yy=y+ky-3; if (yy<0||yy>=H) continue;
      for (int kx=0;kx<7;++kx){
        const int xx=x+kx-3; if (xx<0||xx>=W) continue;
        s += b2f(sa2[base+(size_t)yy*W+xx]) * wl[ch*49+ky*7+kx];
      }
    }
  }
  samap[(size_t)b*HW+i] = f2b(1.f/(1.f+expf(-s)));
}

__global__ void hfinal_k(bf16* __restrict__ hT, const float* __restrict__ scale,
                         const bf16* __restrict__ samap, float* __restrict__ outh, int HW){
  const int px = blockIdx.x*256+threadIdx.x; const int b=blockIdx.y;
  if (px>=HW) return;
  const float sa = b2f(samap[(size_t)b*HW+px]);
  const size_t base = ((size_t)b*HW+px)*16;
  const short8 a=*(const short8*)(hT+base), c8=*(const short8*)(hT+base+8);
  __align__(16) bf16 t[16];
  #pragma unroll
  for (int c=0;c<8;++c){
    const float v=bs2f(a[c])*scale[b*16+c]*sa;
    const float w=bs2f(c8[c])*scale[b*16+8+c]*sa;
    t[c]=f2b(v); t[8+c]=f2b(w);
    outh[((size_t)b*16+c)*HW+px]=v; outh[((size_t)b*16+8+c)*HW+px]=w;
  }
  *(short8*)(hT+base)=*(const short8*)t; *(short8*)(hT+base+8)=*(const short8*)(t+8);
}

extern "C" void kernel_launch(void* const* d_in, const int* in_sizes, int n_in,
                              void* d_out, int out_size, void* d_ws, size_t ws_size,
                              hipStream_t stream)
{
  const float* net   = (const float*)d_in[0];
  const float* inp   = (const float*)d_in[1];
  const float* corr  = (const float*)d_in[2];
  const float* noise = (const float*)d_in[3];
  const float* wc1 = (const float*)d_in[4];  const float* bc1 = (const float*)d_in[5];
  const float* wc2 = (const float*)d_in[6];  const float* bc2 = (const float*)d_in[7];
  const float* wf1 = (const float*)d_in[8];  const float* bf1 = (const float*)d_in[9];
  const float* wf2 = (const float*)d_in[10]; const float* bf2 = (const float*)d_in[11];
  const float* we  = (const float*)d_in[12]; const float* be  = (const float*)d_in[13];
  const float* loc1_w = (const float*)d_in[14]; const float* loc1_b = (const float*)d_in[15];
  const float* loc2_w = (const float*)d_in[16]; const float* loc2_b = (const float*)d_in[17];
  const float* wz = (const float*)d_in[18]; const float* bz = (const float*)d_in[19];
  const float* wr = (const float*)d_in[20]; const float* br = (const float*)d_in[21];
  const float* wq = (const float*)d_in[22]; const float* bq = (const float*)d_in[23];
  const float* ca_w1 = (const float*)d_in[24]; const float* ca_w2 = (const float*)d_in[25];
  const float* sa_w  = (const float*)d_in[26];
  const float* fh1_w = (const float*)d_in[27]; const float* fh1_b = (const float*)d_in[28];
  const float* fh2_w = (const float*)d_in[29]; const float* fh2_b = (const float*)d_in[30];

  const int B = 4, H = 512, W = 512, HW = H*W;
  const size_t U  = 32ull<<20;              // 32 MiB = one 16-ch slab [B][HW][16] bf16
  const size_t SS = (size_t)B*HW*16;        // slab stride in elements
  char* ws = (char*)d_ws;

  // workspace units (256 MiB = 8 units)
  bf16* cor1   = (bf16*)(ws + 0*U);   // u0-1
  bf16* flo1   = (bf16*)(ws + 2*U);   // u2-3
  bf16* flo2   = (bf16*)(ws + 4*U);   // u4-5
  bf16* cnoise = (bf16*)(ws + 6*U);   // u6
  bf16* motion = (bf16*)(ws + 0*U);   // u0-3 (after cor1/flo1 dead)
  bf16* inpT   = (bf16*)(ws + 4*U);   // u4 (after flo2 dead)
  bf16* tbuf   = (bf16*)(ws + 5*U);   // u5
  bf16* netT   = (bf16*)(ws + 6*U);   // u6 (after cnoise dead)
  bf16* flows  = (bf16*)(ws + 7*U);   // u7
  bf16* rh     = (bf16*)(ws + 5*U);   // u5 (after tbuf dead)
  bf16* qb     = (bf16*)(ws + 6*U);   // u6 (after netT dead)
  bf16* hT     = (bf16*)(ws + 5*U);   // u5 (after rh dead)
  bf16* fh1o   = (bf16*)(ws + 0*U);   // u0-3 (after motion dead)
  // CBAM smalls + fh2 weights in u4 (after inpT dead)
  float* part    = (float*)(ws + 4*U);
  float* stats   = (float*)(ws + 4*U + (64<<10));
  float* scale   = (float*)(ws + 4*U + (128<<10));
  bf16*  sa2     = (bf16*)(ws + 4*U + (1<<20));
  bf16*  samap   = (bf16*)(ws + 4*U + (6<<20));
  bf16*  Bw_fh2  = (bf16*)(ws + 4*U + (16<<20));
  float* bias_fh2= (float*)(ws + 4*U + (17<<20));

  float* out_h  = (float*)d_out;
  float* out_df = out_h + (size_t)B*16*HW;
  bf16*  cor2   = (bf16*)d_out;       // d_out h-region scratch (dead before h writes)
  bf16*  zgrg   = (bf16*)d_out;
  bf16*  BwAll  = (bf16*)out_df;      // weights parked in df region (overwritten last)
  float* biasAll= (float*)(BwAll + 190464);

  // Bw element offsets per conv
  const size_t oCor1=0, oCor2=5120, oFlo1=15360, oFlo2=20480, oMo=30720,
               oLoc1=71680, oLoc2=111616, oZgrg=118272, oQ=164352, oFh1=179712;

  const dim3 pgrid((HW+255)/256, B);
  const dim3 cgrid((W/16)*(H/16), 1, B);

  auto WM = [](int b0,int b1,int b2,int b3,int b4,int b5,int b6,int b7,int b8,
               int lo0,int hi0)->WMap{
    WMap m{};
    const int bs[9]={b0,b1,b2,b3,b4,b5,b6,b7,b8};
    for (int g=0; g<9; ++g){ m.base[g]=bs[g]; m.lo[g]=0; m.hi[g]=16; }
    m.lo[0]=lo0; m.hi[0]=hi0;
    return m;
  };

  #define PREP(W1,W2,SPL,B1,B2,MAP,NP,NTP,CO,CIN,T,BWOFF,BIDX) \
    { const int tot = 0; (void)tot; \
      const int total = ((BWOFF##_G)*(NP)*(NTP))*512; \
      prep_w<<<(total+255)/256,256,0,stream>>>(W1,W2,SPL,B1,B2,MAP,NP,NTP,CO,CIN,T, \
        BwAll+BWOFF, biasAll+BIDX*64, total); }

  // --- weight prepass (G encoded per call) ---
  { const int G=1, NP=5, NTP=2, total=G*NP*NTP*512;
    prep_w<<<(total+255)/256,256,0,stream>>>(wc1,nullptr,0,bc1,nullptr,
      WM(0,0,0,0,0,0,0,0,0, 0,3), NP,NTP,32,3,9, BwAll+oCor1, biasAll+0*64, total); }
  { const int G=2, NP=5, NTP=2, total=G*NP*NTP*512;
    prep_w<<<(total+255)/256,256,0,stream>>>(wc2,nullptr,0,bc2,nullptr,
      WM(0,16,0,0,0,0,0,0,0, 0,16), NP,NTP,32,32,9, BwAll+oCor2, biasAll+1*64, total); }
  { const int G=1, NP=5, NTP=2, total=G*NP*NTP*512;
    prep_w<<<(total+255)/256,256,0,stream>>>(wf1,nullptr,0,bf1,nullptr,
      WM(-3,0,0,0,0,0,0,0,0, 3,6), NP,NTP,32,3,9, BwAll+oFlo1, biasAll+2*64, total); }
  { const int G=2, NP=5, NTP=2, total=G*NP*NTP*512;
    prep_w<<<(total+255)/256,256,0,stream>>>(wf2,nullptr,0,bf2,nullptr,
      WM(0,16,0,0,0,0,0,0,0, 0,16), NP,NTP,32,32,9, BwAll+oFlo2, biasAll+3*64, total); }
  { const int G=4, NP=5, NTP=4, total=G*NP*NTP*512;
    prep_w<<<(total+255)/256,256,0,stream>>>(we,nullptr,0,be,nullptr,
      WM(0,16,32,48,0,0,0,0,0, 0,16), NP,NTP,61,64,9, BwAll+oMo, biasAll+4*64, total); }
  { const int G=6, NP=13, NTP=1, total=G*NP*NTP*512;
    prep_w<<<(total+255)/256,256,0,stream>>>(loc1_w,nullptr,0,loc1_b,nullptr,
      WM(0,16,32,48,64,80,0,0,0, 0,16), NP,NTP,16,96,25, BwAll+oLoc1, biasAll+5*64, total); }
  { const int G=1, NP=13, NTP=1, total=G*NP*NTP*512;
    prep_w<<<(total+255)/256,256,0,stream>>>(loc2_w,nullptr,0,loc2_b,nullptr,
      WM(0,0,0,0,0,0,0,0,0, 0,16), NP,NTP,8,16,25, BwAll+oLoc2, biasAll+6*64, total); }
  { const int G=9, NP=5, NTP=2, total=G*NP*NTP*512;
    prep_w<<<(total+255)/256,256,0,stream>>>(wz,wr,16,bz,br,
      WM(0,16,32,48,64,80,96,112,128, 0,16), NP,NTP,32,144,9, BwAll+oZgrg, biasAll+7*64, total); }
  { const int G=6, NP=5, NTP=1, total=G*NP*NTP*512;
    prep_w<<<(total+255)/256,256,0,stream>>>(wq,nullptr,0,bq,nullptr,
      WM(0,16,32,48,64,80,0,0,0, 0,16), NP,NTP,16,96,9, BwAll+oQ, biasAll+8*64, total); }
  { const int G=1, NP=5, NTP=4, total=G*NP*NTP*512;
    prep_w<<<(total+255)/256,256,0,stream>>>(fh1_w,nullptr,0,fh1_b,nullptr,
      WM(0,0,0,0,0,0,0,0,0, 0,16), NP,NTP,64,16,9, BwAll+oFh1, biasAll+9*64, total); }

  // --- motion encoder ---
  pack_cn<<<pgrid,256,0,stream>>>(corr, noise, cnoise, HW);
  { Srcs9 S{}; S.p[0]=cnoise; S.code[0]=0;
    conv_mfma<3,1,2><<<cgrid,256,0,stream>>>(S,1,nullptr,BwAll+oCor1,biasAll+0*64,cor1,SS,nullptr,32,H,W); }
  { Srcs9 S{}; S.p[0]=cor1; S.p[1]=cor1+SS;
    conv_mfma<3,1,2><<<cgrid,256,0,stream>>>(S,2,nullptr,BwAll+oCor2,biasAll+1*64,cor2,SS,nullptr,32,H,W); }
  { Srcs9 S{}; S.p[0]=cnoise;
    conv_mfma<3,1,2><<<cgrid,256,0,stream>>>(S,1,nullptr,BwAll+oFlo1,biasAll+2*64,flo1,SS,nullptr,32,H,W); }
  { Srcs9 S{}; S.p[0]=flo1; S.p[1]=flo1+SS;
    conv_mfma<3,1,2><<<cgrid,256,0,stream>>>(S,2,nullptr,BwAll+oFlo2,biasAll+3*64,flo2,SS,nullptr,32,H,W); }
  { Srcs9 S{}; S.p[0]=cor2; S.p[1]=cor2+SS; S.p[2]=flo2; S.p[3]=flo2+SS;
    conv_mfma<3,1,4><<<cgrid,256,0,stream>>>(S,4,nullptr,BwAll+oMo,biasAll+4*64,motion,SS,nullptr,61,H,W); }
  noise_tail<<<pgrid,256,0,stream>>>(noise, motion+3*SS, HW);

  // --- pack inp/net ---
  pack16<<<pgrid,256,0,stream>>>(inp, inpT, HW);
  pack16<<<pgrid,256,0,stream>>>(net, netT, HW);

  // --- local flows ---
  { Srcs9 S{}; S.p[0]=inpT; S.p[1]=motion; S.p[2]=motion+SS; S.p[3]=motion+2*SS; S.p[4]=motion+3*SS; S.p[5]=netT;
    conv_mfma<5,2,1><<<cgrid,256,0,stream>>>(S,6,nullptr,BwAll+oLoc1,biasAll+5*64,tbuf,SS,nullptr,16,H,W); }
  { Srcs9 S{}; S.p[0]=tbuf;
    conv_mfma<5,0,1><<<cgrid,256,0,stream>>>(S,1,nullptr,BwAll+oLoc2,biasAll+6*64,flows,SS,nullptr,8,H,W); }

  // --- GRU: fused z|r conv with warp-virtual wrapped channels ---
  { Srcs9 S{};
    S.p[0]=netT; S.code[0]=1; S.p[1]=netT; S.code[1]=2;
    S.p[2]=netT; S.code[2]=3; S.p[3]=netT; S.code[3]=4;
    S.p[4]=inpT; S.p[5]=motion; S.p[6]=motion+SS; S.p[7]=motion+2*SS; S.p[8]=motion+3*SS;
    conv_mfma<3,3,2><<<cgrid,256,0,stream>>>(S,9,flows,BwAll+oZgrg,biasAll+7*64,zgrg,SS,nullptr,32,H,W); }
  rh_k<<<pgrid,256,0,stream>>>(zgrg+SS, netT, rh, HW);
  { Srcs9 S{}; S.p[0]=rh; S.p[1]=inpT; S.p[2]=motion; S.p[3]=motion+SS; S.p[4]=motion+2*SS; S.p[5]=motion+3*SS;
    conv_mfma<3,4,1><<<cgrid,256,0,stream>>>(S,6,nullptr,BwAll+oQ,biasAll+8*64,qb,SS,nullptr,16,H,W); }
  h1_k<<<pgrid,256,0,stream>>>(zgrg, qb, net, hT, HW);

  // --- CBAM ---
  castats_p1<<<dim3(32,B),256,0,stream>>>(hT, part, HW);
  castats_p2<<<1,64,0,stream>>>(part, stats, HW);
  cascale_k<<<1,64,0,stream>>>(stats, ca_w1, ca_w2, scale);
  sastats_k<<<pgrid,256,0,stream>>>(hT, scale, sa2, HW);
  saconv_k<<<pgrid,256,0,stream>>>(sa2, sa_w, samap, H, W);
  hfinal_k<<<pgrid,256,0,stream>>>(hT, scale, samap, out_h, HW);

  // --- FlowHead ---
  { const int G=4, NP=5, NTP=1, total=G*NP*NTP*512;   // fh2 weights (u4 now free)
    prep_w<<<(total+255)/256,256,0,stream>>>(fh2_w,nullptr,0,fh2_b,nullptr,
      WM(0,16,32,48,0,0,0,0,0, 0,16), NP,NTP,3,64,9, Bw_fh2, bias_fh2, total); }
  { Srcs9 S{}; S.p[0]=hT;
    conv_mfma<3,1,4><<<cgrid,256,0,stream>>>(S,1,nullptr,BwAll+oFh1,biasAll+9*64,fh1o,SS,nullptr,64,H,W); }
  { Srcs9 S{}; S.p[0]=fh1o; S.p[1]=fh1o+SS; S.p[2]=fh1o+2*SS; S.p[3]=fh1o+3*SS;
    conv_mfma<3,0,1><<<cgrid,256,0,stream>>>(S,4,nullptr,Bw_fh2,bias_fh2,nullptr,SS,out_df,3,H,W); }
}